// Round 1
// baseline (962.535 us; speedup 1.0000x reference)
//
#include <hip/hip_runtime.h>

#define NT      250000
#define NNODES  20000
#define RP      8
#define EMB     64
#define NCLS    16
#define NRELS   64
#define D_BLOCKS 1024   // grid size of k_h2acc (seg0 partials count)

// ---------------- Kernel A: fused per-pair GEMV + softmax ----------------
// l1[p][r] = rm[p,:] @ W1[:,r] + b1[r]
// l2[p][r] = softmax_r(rm[p,:] @ W2[:,r] + b2[r])
__global__ __launch_bounds__(256) void k_gemv(
    const float* __restrict__ rm,
    const float* __restrict__ W1, const float* __restrict__ b1,
    const float* __restrict__ W2, const float* __restrict__ b2,
    float* __restrict__ l1, float* __restrict__ l2)
{
    int p = blockIdx.x * blockDim.x + threadIdx.x;
    if (p >= NT) return;
    float a1[RP], a2[RP];
#pragma unroll
    for (int r = 0; r < RP; ++r) { a1[r] = b1[r]; a2[r] = b2[r]; }
    const float4* row = reinterpret_cast<const float4*>(rm + (size_t)p * NRELS);
#pragma unroll 4
    for (int k4 = 0; k4 < NRELS / 4; ++k4) {
        float4 v = row[k4];
        float xs[4] = {v.x, v.y, v.z, v.w};
#pragma unroll
        for (int j = 0; j < 4; ++j) {
            float x = xs[j];
            int k = k4 * 4 + j;
#pragma unroll
            for (int r = 0; r < RP; ++r) {
                a1[r] = fmaf(x, W1[k * RP + r], a1[r]);
                a2[r] = fmaf(x, W2[k * RP + r], a2[r]);
            }
        }
    }
    // softmax over a2
    float m = a2[0];
#pragma unroll
    for (int r = 1; r < RP; ++r) m = fmaxf(m, a2[r]);
    float s = 0.f;
#pragma unroll
    for (int r = 0; r < RP; ++r) { a2[r] = __expf(a2[r] - m); s += a2[r]; }
    float inv = 1.0f / s;
#pragma unroll
    for (int r = 0; r < RP; ++r) a2[r] *= inv;

    float4* o1 = reinterpret_cast<float4*>(l1 + (size_t)p * RP);
    float4* o2 = reinterpret_cast<float4*>(l2 + (size_t)p * RP);
    o1[0] = make_float4(a1[0], a1[1], a1[2], a1[3]);
    o1[1] = make_float4(a1[4], a1[5], a1[6], a1[7]);
    o2[0] = make_float4(a2[0], a2[1], a2[2], a2[3]);
    o2[1] = make_float4(a2[4], a2[5], a2[6], a2[7]);
}

// ---------------- Kernel B0: segment-0 sums (r == 0 for all pairs) ----------------
__global__ __launch_bounds__(256) void k_seg0(
    const float* __restrict__ l1, const float* __restrict__ l2,
    float* __restrict__ colsum, float* __restrict__ rowsum)
{
    __shared__ float red1[256], red2[256];
    float s1 = 0.f, s2 = 0.f;
    for (int p = blockIdx.x * blockDim.x + threadIdx.x; p < NT; p += gridDim.x * blockDim.x) {
        s1 += l1[(size_t)p * RP];
        s2 += l2[(size_t)p * RP];
    }
    red1[threadIdx.x] = s1; red2[threadIdx.x] = s2;
    __syncthreads();
    for (int off = 128; off > 0; off >>= 1) {
        if (threadIdx.x < off) {
            red1[threadIdx.x] += red1[threadIdx.x + off];
            red2[threadIdx.x] += red2[threadIdx.x + off];
        }
        __syncthreads();
    }
    if (threadIdx.x == 0) {
        atomicAdd(&colsum[0], red1[0]);
        atomicAdd(&rowsum[0], red2[0]);
    }
}

// ---------------- Kernel B: segment sums for r >= 1 ----------------
// colsum[o*r] += l1[p][r]; rowsum[s*r] += l2[p][r]
__global__ __launch_bounds__(256) void k_segsum(
    const float* __restrict__ l1, const float* __restrict__ l2,
    const int* __restrict__ hrow, const int* __restrict__ vcol,
    float* __restrict__ colsum, float* __restrict__ rowsum)
{
    int p = blockIdx.x * blockDim.x + threadIdx.x;
    if (p >= NT) return;
    int s = hrow[p], o = vcol[p];
    const float4* L1 = reinterpret_cast<const float4*>(l1 + (size_t)p * RP);
    const float4* L2 = reinterpret_cast<const float4*>(l2 + (size_t)p * RP);
    float4 a = L1[0], b = L1[1], c = L2[0], d = L2[1];
    float v1[RP] = {a.x, a.y, a.z, a.w, b.x, b.y, b.z, b.w};
    float v2[RP] = {c.x, c.y, c.z, c.w, d.x, d.y, d.z, d.w};
#pragma unroll
    for (int r = 1; r < RP; ++r) {
        atomicAdd(&colsum[o * r], v1[r]);
        atomicAdd(&rowsum[s * r], v2[r]);
    }
}

// ---------------- Kernel C: h[s] += sum_r (l1[p][r]/colsum[o*r]) * W1row[o*r] ----------------
// one wave (64 lanes == EMB) per pair
__global__ __launch_bounds__(256) void k_hacc(
    const float* __restrict__ l1, const float* __restrict__ colsum,
    const int* __restrict__ hrow, const int* __restrict__ vcol,
    const float* __restrict__ w1, float* __restrict__ h)
{
    int wave = (int)((blockIdx.x * blockDim.x + threadIdx.x) >> 6);
    int lane = threadIdx.x & 63;
    if (wave >= NT) return;
    int p = wave;
    int s = hrow[p], o = vcol[p];
    float acc = 0.f;
#pragma unroll
    for (int r = 0; r < RP; ++r) {
        int seg = o * r;
        float coef = l1[(size_t)p * RP + r] / colsum[seg];
        acc = fmaf(coef, w1[(size_t)seg * EMB + lane], acc);
    }
    atomicAdd(&h[(size_t)s * EMB + lane], acc);
}

// ---------------- Kernel D: h2[s*r] += (l2[p][r]/max(rowsum[s*r],1e-6)) * relu(h[o]+bias1) ----------------
// grid-stride waves; seg==0 contributions go to per-block partials
__global__ __launch_bounds__(256) void k_h2acc(
    const float* __restrict__ l2, const float* __restrict__ rowsum,
    const int* __restrict__ hrow, const int* __restrict__ vcol,
    const float* __restrict__ h, const float* __restrict__ bias1,
    float* __restrict__ h2, float* __restrict__ seg0p)
{
    int lane = threadIdx.x & 63;
    int wave = (int)((blockIdx.x * blockDim.x + threadIdx.x) >> 6);
    int nwaves = (int)((gridDim.x * blockDim.x) >> 6);
    float b = bias1[lane];
    float acc0 = 0.f;
    for (int p = wave; p < NT; p += nwaves) {
        int s = hrow[p], o = vcol[p];
        float hv = fmaxf(h[(size_t)o * EMB + lane] + b, 0.f);
#pragma unroll
        for (int r = 0; r < RP; ++r) {
            int seg = s * r;
            float coef = l2[(size_t)p * RP + r] / fmaxf(rowsum[seg], 1e-6f);
            float contrib = coef * hv;
            if (seg == 0) {           // r==0 (always) or s==0; wave-uniform branch
                acc0 += contrib;
            } else {
                atomicAdd(&h2[(size_t)seg * EMB + lane], contrib);
            }
        }
    }
    __shared__ float red[256];
    red[threadIdx.x] = acc0;
    __syncthreads();
    if (threadIdx.x < 64) {
        float v = red[threadIdx.x] + red[threadIdx.x + 64] +
                  red[threadIdx.x + 128] + red[threadIdx.x + 192];
        seg0p[(size_t)blockIdx.x * EMB + threadIdx.x] = v;
    }
}

// ---------------- Kernel D2: reduce seg0 partials into h2[0] ----------------
__global__ __launch_bounds__(256) void k_seg0h2(
    const float* __restrict__ seg0p, float* __restrict__ h2)
{
    __shared__ float red[256];
    int e = threadIdx.x & 63, c = threadIdx.x >> 6;
    float s = 0.f;
    for (int b = c; b < D_BLOCKS; b += 4) s += seg0p[(size_t)b * EMB + e];
    red[threadIdx.x] = s;
    __syncthreads();
    if (threadIdx.x < 64) {
        h2[threadIdx.x] += red[threadIdx.x] + red[threadIdx.x + 64] +
                           red[threadIdx.x + 128] + red[threadIdx.x + 192];
    }
}

// ---------------- Kernel E0: init logits with bias2 ----------------
__global__ __launch_bounds__(256) void k_outinit(float* __restrict__ out, const float* __restrict__ b2)
{
    int i = blockIdx.x * blockDim.x + threadIdx.x;
    if (i < NNODES * NCLS) out[i] = b2[i & (NCLS - 1)];
}

// ---------------- Kernel E: logits[n][c] += sum_h w2[r][h][c] * h2[r*N+n][h] ----------------
// one thread per (n, r)
__global__ __launch_bounds__(256) void k_logits(
    const float* __restrict__ h2, const float* __restrict__ w2,
    float* __restrict__ out)
{
    __shared__ float w2s[RP * EMB * NCLS];
    for (int i = threadIdx.x; i < RP * EMB * NCLS; i += blockDim.x) w2s[i] = w2[i];
    __syncthreads();
    int tid = blockIdx.x * blockDim.x + threadIdx.x;
    if (tid >= NNODES * RP) return;
    int n = tid % NNODES;
    int r = tid / NNODES;
    const float4* hr = reinterpret_cast<const float4*>(h2 + ((size_t)r * NNODES + n) * EMB);
    float acc[NCLS];
#pragma unroll
    for (int c = 0; c < NCLS; ++c) acc[c] = 0.f;
#pragma unroll
    for (int h4 = 0; h4 < EMB / 4; ++h4) {
        float4 v = hr[h4];
        float xs[4] = {v.x, v.y, v.z, v.w};
#pragma unroll
        for (int j = 0; j < 4; ++j) {
            int hh = h4 * 4 + j;
#pragma unroll
            for (int c = 0; c < NCLS; ++c)
                acc[c] = fmaf(xs[j], w2s[(r * EMB + hh) * NCLS + c], acc[c]);
        }
    }
    float* op = out + (size_t)n * NCLS;
#pragma unroll
    for (int c = 0; c < NCLS; ++c) atomicAdd(&op[c], acc[c]);
}

extern "C" void kernel_launch(void* const* d_in, const int* in_sizes, int n_in,
                              void* d_out, int out_size, void* d_ws, size_t ws_size,
                              hipStream_t stream)
{
    const float* rm    = (const float*)d_in[0];
    const int*   hrow  = (const int*)d_in[1];
    // d_in[2] = hcol (== o*r, recomputed), d_in[3] = vrow (== s*r, recomputed)
    const int*   vcol  = (const int*)d_in[4];
    const float* W1    = (const float*)d_in[5];
    const float* b1    = (const float*)d_in[6];
    const float* W2    = (const float*)d_in[7];
    const float* b2    = (const float*)d_in[8];
    const float* w1    = (const float*)d_in[9];
    const float* w2    = (const float*)d_in[10];
    const float* bias1 = (const float*)d_in[11];
    const float* bias2 = (const float*)d_in[12];
    float* out = (float*)d_out;

    float* ws     = (float*)d_ws;
    float* l1     = ws;                       // 2,000,000
    float* l2     = l1 + 2000000;             // 2,000,000
    float* colsum = l2 + 2000000;             // 160,000
    float* rowsum = colsum + 160000;          // 160,000
    float* h      = rowsum + 160000;          // 1,280,000
    float* h2     = h + 1280000;              // 10,240,000
    float* seg0p  = h2 + 10240000;            // D_BLOCKS*64 = 65,536
    // total = 15,905,536 floats ~= 63.6 MB

    // zero accumulators (must happen every call: graph replays accumulate atomics)
    hipMemsetAsync(colsum, 0, (size_t)(160000 + 160000 + 1280000) * sizeof(float), stream);
    hipMemsetAsync(h2, 0, (size_t)10240000 * sizeof(float), stream);

    k_gemv  <<<(NT + 255) / 256, 256, 0, stream>>>(rm, W1, b1, W2, b2, l1, l2);
    k_seg0  <<<512, 256, 0, stream>>>(l1, l2, colsum, rowsum);
    k_segsum<<<(NT + 255) / 256, 256, 0, stream>>>(l1, l2, hrow, vcol, colsum, rowsum);
    k_hacc  <<<(NT * 64 + 255) / 256, 256, 0, stream>>>(l1, colsum, hrow, vcol, w1, h);
    k_h2acc <<<D_BLOCKS, 256, 0, stream>>>(l2, rowsum, hrow, vcol, h, bias1, h2, seg0p);
    k_seg0h2<<<1, 256, 0, stream>>>(seg0p, h2);
    k_outinit<<<(NNODES * NCLS + 255) / 256, 256, 0, stream>>>(out, bias2);
    k_logits<<<(NNODES * RP + 255) / 256, 256, 0, stream>>>(h2, w2, out);
}

// Round 2
// 329.760 us; speedup vs baseline: 2.9189x; 2.9189x over previous
//
#include <hip/hip_runtime.h>

#define NT      250000
#define NN      20000
#define RP      8
#define EMB     64
#define NCLS    16
#define NRELS   64

// ---------------- A: per-pair GEMV + softmax + colsum scatter ----------------
__global__ __launch_bounds__(256) void k_gemv(
    const float* __restrict__ rm,
    const float* __restrict__ W1, const float* __restrict__ b1,
    const float* __restrict__ W2, const float* __restrict__ b2,
    const int* __restrict__ vcol,
    float* __restrict__ l1, float* __restrict__ l2,
    float* __restrict__ colsum)
{
    int p = blockIdx.x * blockDim.x + threadIdx.x;
    float c0 = 0.f;
    if (p < NT) {
        float a1[RP], a2[RP];
#pragma unroll
        for (int r = 0; r < RP; ++r) { a1[r] = b1[r]; a2[r] = b2[r]; }
        const float4* row = reinterpret_cast<const float4*>(rm + (size_t)p * NRELS);
#pragma unroll 4
        for (int k4 = 0; k4 < NRELS / 4; ++k4) {
            float4 v = row[k4];
            float xs[4] = {v.x, v.y, v.z, v.w};
#pragma unroll
            for (int j = 0; j < 4; ++j) {
                float x = xs[j];
                int k = k4 * 4 + j;
#pragma unroll
                for (int r = 0; r < RP; ++r) {
                    a1[r] = fmaf(x, W1[k * RP + r], a1[r]);
                    a2[r] = fmaf(x, W2[k * RP + r], a2[r]);
                }
            }
        }
        float m = a2[0];
#pragma unroll
        for (int r = 1; r < RP; ++r) m = fmaxf(m, a2[r]);
        float s = 0.f;
#pragma unroll
        for (int r = 0; r < RP; ++r) { a2[r] = __expf(a2[r] - m); s += a2[r]; }
        float inv = 1.0f / s;
#pragma unroll
        for (int r = 0; r < RP; ++r) a2[r] *= inv;

        c0 = a1[0];
        int o = vcol[p];
#pragma unroll
        for (int r = 1; r < RP; ++r) atomicAdd(&colsum[o * r], a1[r]);

        float4* o1 = reinterpret_cast<float4*>(l1 + (size_t)p * RP);
        float4* o2 = reinterpret_cast<float4*>(l2 + (size_t)p * RP);
        o1[0] = make_float4(a1[0], a1[1], a1[2], a1[3]);
        o1[1] = make_float4(a1[4], a1[5], a1[6], a1[7]);
        o2[0] = make_float4(a2[0], a2[1], a2[2], a2[3]);
        o2[1] = make_float4(a2[4], a2[5], a2[6], a2[7]);
    }
    // block-reduce r==0 contributions -> colsum[0] (one atomic per block)
    __shared__ float red[256];
    red[threadIdx.x] = c0;
    __syncthreads();
    for (int off = 128; off > 0; off >>= 1) {
        if (threadIdx.x < off) red[threadIdx.x] += red[threadIdx.x + off];
        __syncthreads();
    }
    if (threadIdx.x == 0) atomicAdd(&colsum[0], red[0]);
}

// ---------------- CSR offsets: hrow[0:NT] is sorted (np.unique axis=0) ----------------
__global__ __launch_bounds__(256) void k_rowptr(
    const int* __restrict__ hrow, int* __restrict__ rowptr)
{
    int i = blockIdx.x * blockDim.x + threadIdx.x;
    if (i > NN) return;
    int lo = 0, hi = NT;
    while (lo < hi) { int mid = (lo + hi) >> 1; if (hrow[mid] < i) lo = mid + 1; else hi = mid; }
    rowptr[i] = lo;
}

// ---------------- C: one wave per node s, no atomics ----------------
// h[s][e] = relu(bias1[e] + sum_{p in seg(s)} sum_r (l1[p][r]/colsum[o*r]) * w1[o*r][e])
__global__ __launch_bounds__(256) void k_h(
    const float* __restrict__ l1, const float* __restrict__ colsum,
    const int* __restrict__ rowptr, const int* __restrict__ vcol,
    const float* __restrict__ w1, const float* __restrict__ bias1,
    float* __restrict__ h)
{
    int wave = (int)((blockIdx.x * blockDim.x + threadIdx.x) >> 6);
    int lane = threadIdx.x & 63;
    if (wave >= NN) return;
    int s = wave;
    int pb = rowptr[s], pe = rowptr[s + 1];
    float acc = 0.f;
    float c0 = 0.f;                      // r==0 row factored: seg=0, same w1 row
    for (int p = pb; p < pe; ++p) {
        int o = vcol[p];
        const float* lp = l1 + (size_t)p * RP;
        c0 += lp[0];
#pragma unroll
        for (int r = 1; r < RP; ++r) {
            int seg = o * r;
            float coef = lp[r] / colsum[seg];
            acc = fmaf(coef, w1[(size_t)seg * EMB + lane], acc);
        }
    }
    acc = fmaf(c0 / colsum[0], w1[lane], acc);
    h[(size_t)s * EMB + lane] = fmaxf(acc + bias1[lane], 0.f);
}

// ---------------- D: one wave per node s; register-resident 8x64 block ----------------
// Writes raw (pre-division) sums; seg0 via partials; rowsum scatter (depth<=8)
__global__ __launch_bounds__(256) void k_h2(
    const float* __restrict__ l2, const int* __restrict__ rowptr,
    const int* __restrict__ vcol, const float* __restrict__ h,
    float* __restrict__ h2raw, float* __restrict__ rowsum,
    float* __restrict__ Abuf0, float* __restrict__ rs0part)
{
    int wave = (int)((blockIdx.x * blockDim.x + threadIdx.x) >> 6);
    int lane = threadIdx.x & 63;
    if (wave >= NN) return;
    int s = wave;
    int pb = rowptr[s], pe = rowptr[s + 1];
    float acc[RP], rs[RP];
#pragma unroll
    for (int r = 0; r < RP; ++r) { acc[r] = 0.f; rs[r] = 0.f; }
    for (int p = pb; p < pe; ++p) {
        int o = vcol[p];
        float hv = h[(size_t)o * EMB + lane];
        const float* lp = l2 + (size_t)p * RP;
#pragma unroll
        for (int r = 0; r < RP; ++r) {
            float lv = lp[r];
            acc[r] = fmaf(lv, hv, acc[r]);
            rs[r] += lv;
        }
    }
    if (s == 0) {
        // all r give seg 0
        float a0 = 0.f, r0 = 0.f;
#pragma unroll
        for (int r = 0; r < RP; ++r) { a0 += acc[r]; r0 += rs[r]; }
        Abuf0[lane] = a0;
        if (lane == 0) rs0part[0] = r0;
    } else {
        Abuf0[(size_t)s * EMB + lane] = acc[0];
        if (lane == 0) rs0part[s] = rs[0];
#pragma unroll
        for (int r = 1; r < RP; ++r) {
            int seg = s * r;
            atomicAdd(&h2raw[(size_t)seg * EMB + lane], acc[r]);
            if (lane == 0) atomicAdd(&rowsum[seg], rs[r]);
        }
    }
}

// ---------------- reduce seg-0 partials ----------------
__global__ __launch_bounds__(256) void k_red0(
    const float* __restrict__ Abuf0, const float* __restrict__ rs0part,
    float* __restrict__ h2raw, float* __restrict__ rowsum)
{
    __shared__ float red[256];
    if (blockIdx.x < 64) {
        int lane = threadIdx.x & 63, w = threadIdx.x >> 6;
        float sum = 0.f;
        for (int ss = blockIdx.x + 64 * w; ss < NN; ss += 256)
            sum += Abuf0[(size_t)ss * EMB + lane];
        red[threadIdx.x] = sum;
        __syncthreads();
        if (threadIdx.x < 64) {
            float v = red[threadIdx.x] + red[threadIdx.x + 64] +
                      red[threadIdx.x + 128] + red[threadIdx.x + 192];
            atomicAdd(&h2raw[threadIdx.x], v);
        }
    } else {
        float sum = 0.f;
        for (int ssp = (int)threadIdx.x; ssp < NN; ssp += 256) sum += rs0part[ssp];
        red[threadIdx.x] = sum;
        __syncthreads();
        for (int off = 128; off > 0; off >>= 1) {
            if (threadIdx.x < off) red[threadIdx.x] += red[threadIdx.x + off];
            __syncthreads();
        }
        if (threadIdx.x == 0) atomicAdd(&rowsum[0], red[0]);
    }
}

// ---------------- E: wave per node n; fused /rowsum + einsum + bias2 ----------------
__global__ __launch_bounds__(1024) void k_logits(
    const float* __restrict__ h2raw, const float* __restrict__ rowsum,
    const float* __restrict__ w2, const float* __restrict__ bias2,
    float* __restrict__ out)
{
    __shared__ float w2s[RP * EMB * NCLS];   // 32 KB
    for (int i = threadIdx.x; i < RP * EMB * NCLS; i += 1024) w2s[i] = w2[i];
    __syncthreads();
    int wv = threadIdx.x >> 6, lane = threadIdx.x & 63;
    int n = blockIdx.x * 16 + wv;            // grid=1250 -> n < 20000 exactly
    int c = lane & 15, es = lane >> 4;
    float acc = 0.f;
#pragma unroll
    for (int r = 0; r < RP; ++r) {
        size_t k = (size_t)r * NN + n;
        float hv = h2raw[k * EMB + lane] / fmaxf(rowsum[k], 1e-6f);
#pragma unroll
        for (int eo = 0; eo < 16; ++eo) {
            float he = __shfl(hv, es * 16 + eo, 64);
            acc = fmaf(he, w2s[(r * EMB + es * 16 + eo) * NCLS + c], acc);
        }
    }
    acc += __shfl_xor(acc, 16, 64);
    acc += __shfl_xor(acc, 32, 64);
    if (lane < 16) out[(size_t)n * NCLS + lane] = acc + bias2[lane];
}

extern "C" void kernel_launch(void* const* d_in, const int* in_sizes, int n_in,
                              void* d_out, int out_size, void* d_ws, size_t ws_size,
                              hipStream_t stream)
{
    const float* rm    = (const float*)d_in[0];
    const int*   hrow  = (const int*)d_in[1];   // sorted source nodes (first NT of tile)
    const int*   vcol  = (const int*)d_in[4];   // object nodes
    const float* W1    = (const float*)d_in[5];
    const float* b1    = (const float*)d_in[6];
    const float* W2    = (const float*)d_in[7];
    const float* b2    = (const float*)d_in[8];
    const float* w1    = (const float*)d_in[9];
    const float* w2    = (const float*)d_in[10];
    const float* bias1 = (const float*)d_in[11];
    const float* bias2 = (const float*)d_in[12];
    float* out = (float*)d_out;

    float* ws      = (float*)d_ws;
    float* l1      = ws;                    // 2,000,000
    float* l2      = ws + 2000000;          // 2,000,000
    float* colsum  = ws + 4000000;          // 160,000
    float* rowsum  = ws + 4160000;          // 160,000
    float* h       = ws + 4320000;          // 1,280,000
    float* h2raw   = ws + 5600000;          // 10,240,000
    int*   rowptr  = (int*)(ws + 15840000); // 20,001 ints
    // Abuf0/rs0part overlay l1 (dead after k_h)
    float* Abuf0   = ws;                    // 1,280,000
    float* rs0part = ws + 1280000;          // 20,000

    // zero the scatter targets (graph replays accumulate atomics)
    hipMemsetAsync(colsum, 0, (size_t)320000 * sizeof(float), stream);            // colsum+rowsum
    hipMemsetAsync(h2raw, 0, (size_t)10240000 * sizeof(float), stream);

    k_rowptr<<<(NN + 256) / 256, 256, 0, stream>>>(hrow, rowptr);
    k_gemv  <<<(NT + 255) / 256, 256, 0, stream>>>(rm, W1, b1, W2, b2, vcol, l1, l2, colsum);
    k_h     <<<(NN * 64) / 256, 256, 0, stream>>>(l1, colsum, rowptr, vcol, w1, bias1, h);
    k_h2    <<<(NN * 64) / 256, 256, 0, stream>>>(l2, rowptr, vcol, h, h2raw, rowsum, Abuf0, rs0part);
    k_red0  <<<65, 256, 0, stream>>>(Abuf0, rs0part, h2raw, rowsum);
    k_logits<<<NN / 16, 1024, 0, stream>>>(h2raw, rowsum, w2, bias2, out);
}